// Round 3
// baseline (259.818 us; speedup 1.0000x reference)
//
#include <hip/hip_runtime.h>

#define N_NODES 50000
#define N_EDGES 800000
// D_FEAT=64, D_EDGE=16, D_HID=16, D_MSG=64, D_OUT=64

__device__ __forceinline__ unsigned fkey(float f) {
    unsigned u = __float_as_uint(f);
    return (u & 0x80000000u) ? ~u : (u | 0x80000000u);
}
// key(-inf) = ~0xFF800000 = 0x007FFFFF
#define KEY_NEG_INF 0x007FFFFFu

// wave-local LDS fence: per-wave private LDS region, DS pipe is in-order per
// wave; asm waitcnt + sched_barrier per guide rule 18. No s_barrier needed.
__device__ __forceinline__ void wave_lds_fence() {
    asm volatile("s_waitcnt lgkmcnt(0)" ::: "memory");
    __builtin_amdgcn_sched_barrier(0);
}

// ---------------- init: fill rkey with key(-inf) ----------------
__global__ __launch_bounds__(256) void init_kernel(unsigned* __restrict__ rkey) {
    const int i = blockIdx.x * 256 + threadIdx.x;  // 3125*256 = 800000 uint4 exact
    reinterpret_cast<uint4*>(rkey)[i] =
        make_uint4(KEY_NEG_INF, KEY_NEG_INF, KEY_NEG_INF, KEY_NEG_INF);
}

// ---------------- CSR build ----------------
__global__ __launch_bounds__(256) void zero_deg_kernel(unsigned* __restrict__ deg) {
    const int i = blockIdx.x * 256 + threadIdx.x;
    if (i < N_NODES) deg[i] = 0;
}

__global__ __launch_bounds__(256) void hist_kernel(const int* __restrict__ dst,
                                                   unsigned* __restrict__ deg) {
    const int e = blockIdx.x * 256 + threadIdx.x;  // exact grid
    atomicAdd(&deg[dst[e]], 1u);
}

// one block, 1024 threads: exclusive prefix sum of deg[50000] -> cursor
#define SCAN_C 49  // 1024*49 = 50176 >= 50000
__global__ __launch_bounds__(1024) void scan_kernel(const unsigned* __restrict__ deg,
                                                    unsigned* __restrict__ cursor) {
    __shared__ unsigned sums[1024];
    const int t = threadIdx.x;
    unsigned local[SCAN_C];
    unsigned s = 0;
#pragma unroll
    for (int i = 0; i < SCAN_C; ++i) {
        int idx = t * SCAN_C + i;
        unsigned v = (idx < N_NODES) ? deg[idx] : 0u;
        local[i] = s;  // exclusive within chunk
        s += v;
    }
    sums[t] = s;
    __syncthreads();
    for (int d = 1; d < 1024; d <<= 1) {
        unsigned v = (t >= d) ? sums[t - d] : 0u;
        __syncthreads();
        sums[t] += v;
        __syncthreads();
    }
    const unsigned off = (t > 0) ? sums[t - 1] : 0u;
#pragma unroll
    for (int i = 0; i < SCAN_C; ++i) {
        int idx = t * SCAN_C + i;
        if (idx < N_NODES) cursor[idx] = off + local[i];
    }
}

__global__ __launch_bounds__(256) void scatter_kernel(const int* __restrict__ dst,
                                                      unsigned* __restrict__ cursor,
                                                      unsigned* __restrict__ perm,
                                                      int* __restrict__ dst_sorted) {
    const int e = blockIdx.x * 256 + threadIdx.x;  // exact grid
    const int d = dst[e];
    const unsigned pos = atomicAdd(&cursor[d], 1u);
    perm[pos] = (unsigned)e;
    dst_sorted[pos] = d;
}

// ---------------- edge kernel (CSR order, segmented reduce) ----------------
// 4 independent waves/block, wave = 64 CSR slots. Thread-per-edge MLP with
// uniform (s_load) weights; LDS transpose; per-quarter serial segmented max
// scan; plain coalesced store for complete segments, atomicMax only for
// boundary pieces.
__global__ __launch_bounds__(256) void edge_csr_kernel(
    const float* __restrict__ x, const float* __restrict__ ef,
    const int* __restrict__ src,
    const unsigned* __restrict__ perm, const int* __restrict__ dst_sorted,
    const float* __restrict__ W1, const float* __restrict__ b1,
    const float* __restrict__ W2, const float* __restrict__ b2,
    unsigned* __restrict__ rkey)
{
    const int lane = threadIdx.x & 63;
    const int w    = threadIdx.x >> 6;
    const int wave = blockIdx.x * 4 + w;
    const int base = wave * 64;
    const int slot = base + lane;

    __shared__ unsigned mld[4][64][17];
    __shared__ int      dldA[4][66];   // [w][0]=dst before base, [w][1+i]=slot i, [w][65]=dst after
    int* dld = &dldA[w][1];

    const int e = (int)perm[slot];
    const int d = dst_sorted[slot];
    dld[lane] = d;
    if (lane == 0)  dld[-1] = (base == 0) ? -1 : dst_sorted[base - 1];
    if (lane == 63) dld[64] = (base + 64 >= N_EDGES) ? -1 : dst_sorted[base + 64];

    // ---- load inputs: [edge_feats(16), x[src](64)] ----
    float in[80];
    const float4* efp = reinterpret_cast<const float4*>(ef) + (size_t)e * 4;
#pragma unroll
    for (int c = 0; c < 4; ++c) {
        float4 t = efp[c];
        in[4*c+0]=t.x; in[4*c+1]=t.y; in[4*c+2]=t.z; in[4*c+3]=t.w;
    }
    const int s = src[e];
    const float4* xp = reinterpret_cast<const float4*>(x) + (size_t)s * 16;
#pragma unroll
    for (int c = 0; c < 16; ++c) {
        float4 t = xp[c];
        in[16+4*c+0]=t.x; in[16+4*c+1]=t.y; in[16+4*c+2]=t.z; in[16+4*c+3]=t.w;
    }

    // ---- hidden: h = relu(in @ W1 + b1), W1[80][16] (uniform -> s_load) ----
    float h[16];
#pragma unroll
    for (int k = 0; k < 16; ++k) h[k] = b1[k];
#pragma unroll
    for (int i = 0; i < 80; ++i)
#pragma unroll
        for (int k = 0; k < 16; ++k)
            h[k] = fmaf(in[i], W1[i*16 + k], h[k]);
#pragma unroll
    for (int k = 0; k < 16; ++k) h[k] = fmaxf(h[k], 0.0f);

    const int q  = lane >> 4;   // quarter 0..3
    const int jj = lane & 15;   // feature within chunk

    // ---- output in chunks of 16 feats ----
#pragma unroll
    for (int j0 = 0; j0 < 64; j0 += 16) {
        float m[16];
#pragma unroll
        for (int t = 0; t < 16; ++t) m[t] = b2[j0 + t];
#pragma unroll
        for (int k = 0; k < 16; ++k)
#pragma unroll
            for (int t = 0; t < 16; ++t)
                m[t] = fmaf(h[k], W2[k*64 + j0 + t], m[t]);

        wave_lds_fence();               // prior chunk's scan reads done
#pragma unroll
        for (int t = 0; t < 16; ++t) mld[w][lane][t] = fkey(m[t]);
        wave_lds_fence();               // writes (incl. dld) visible to wave

        // ---- segmented max scan over this quarter's 16 slots ----
        const int s0 = q * 16;
        unsigned run = KEY_NEG_INF;
        int  dprev = dld[s0 - 1];       // dst just before the quarter (-1 sentinel)
        bool phead = (dld[s0] != dprev);
        dprev = dld[s0];
        run = mld[w][s0][jj];
#pragma unroll
        for (int i = 1; i < 16; ++i) {
            const int ss = s0 + i;
            const int ds = dld[ss];
            if (ds != dprev) {          // piece ends at ss-1; flush it
                unsigned* addr = &rkey[((size_t)dprev << 6) + (unsigned)(j0 + jj)];
                if (phead) *addr = run;          // head && tail(true here)
                else       atomicMax(addr, run);
                run = KEY_NEG_INF;
                phead = true;
            }
            run = max(run, mld[w][ss][jj]);
            dprev = ds;
        }
        const bool ptail = (dld[s0 + 16] != dprev);  // dld[64] covers q==3
        unsigned* addr = &rkey[((size_t)dprev << 6) + (unsigned)(j0 + jj)];
        if (phead && ptail) *addr = run;
        else                atomicMax(addr, run);
    }
}

// ---------------- node kernel: decode + update MLP ----------------
// rkey and out alias (both d_out); this thread reads its own row before
// writing it. No __restrict__ on those two.
__global__ __launch_bounds__(256) void node_kernel(
    const float* __restrict__ x, const unsigned* rkey,
    const float* __restrict__ W1, const float* __restrict__ b1,
    const float* __restrict__ W2, const float* __restrict__ b2,
    float* out)
{
    const int v = blockIdx.x * 256 + threadIdx.x;
    if (v >= N_NODES) return;

    float in[128];
    const float4* xp = reinterpret_cast<const float4*>(x) + (size_t)v * 16;
#pragma unroll
    for (int c = 0; c < 16; ++c) {
        float4 t = xp[c];
        in[4*c+0]=t.x; in[4*c+1]=t.y; in[4*c+2]=t.z; in[4*c+3]=t.w;
    }
    const uint4* rp = reinterpret_cast<const uint4*>(rkey) + (size_t)v * 16;
#pragma unroll
    for (int c = 0; c < 16; ++c) {
        uint4 t = rp[c];
        unsigned ks[4] = {t.x, t.y, t.z, t.w};
#pragma unroll
        for (int qq = 0; qq < 4; ++qq) {
            unsigned k = ks[qq];
            unsigned u = (k & 0x80000000u) ? (k ^ 0x80000000u) : ~k;
            float f = __uint_as_float(u);
            if (!(f >= -3.402823466e38f && f <= 3.402823466e38f)) f = 0.0f;
            in[64 + 4*c + qq] = f;
        }
    }

    float h[16];
#pragma unroll
    for (int k = 0; k < 16; ++k) h[k] = b1[k];
#pragma unroll
    for (int i = 0; i < 128; ++i)
#pragma unroll
        for (int k = 0; k < 16; ++k)
            h[k] = fmaf(in[i], W1[i*16 + k], h[k]);
#pragma unroll
    for (int k = 0; k < 16; ++k) h[k] = fmaxf(h[k], 0.0f);

    float* op = out + (size_t)v * 64;
#pragma unroll
    for (int c = 0; c < 16; ++c) {
        float oo[4];
#pragma unroll
        for (int qq = 0; qq < 4; ++qq) {
            float a = b2[4*c + qq];
#pragma unroll
            for (int k = 0; k < 16; ++k)
                a = fmaf(h[k], W2[k*64 + 4*c + qq], a);
            oo[qq] = a;
        }
        float4 o; o.x=oo[0]; o.y=oo[1]; o.z=oo[2]; o.w=oo[3];
        reinterpret_cast<float4*>(op)[c] = o;
    }
}

// ---------------- fallback edge kernel (direct atomics, round-2 path) ------
__global__ __launch_bounds__(64) void edge_kernel(
    const float* __restrict__ x, const float* __restrict__ ef,
    const int* __restrict__ src, const int* __restrict__ dst,
    const float* __restrict__ W1, const float* __restrict__ b1,
    const float* __restrict__ W2, const float* __restrict__ b2,
    unsigned* __restrict__ rkey)
{
    const int lane = threadIdx.x;
    const int e    = blockIdx.x * 64 + lane;

    __shared__ unsigned mld[64][17];
    __shared__ int      dld[64];

    float in[80];
    const float4* efp = reinterpret_cast<const float4*>(ef) + (size_t)e * 4;
#pragma unroll
    for (int c = 0; c < 4; ++c) {
        float4 t = efp[c];
        in[4*c+0]=t.x; in[4*c+1]=t.y; in[4*c+2]=t.z; in[4*c+3]=t.w;
    }
    const int s = src[e];
    dld[lane] = dst[e];
    const float4* xp = reinterpret_cast<const float4*>(x) + (size_t)s * 16;
#pragma unroll
    for (int c = 0; c < 16; ++c) {
        float4 t = xp[c];
        in[16+4*c+0]=t.x; in[16+4*c+1]=t.y; in[16+4*c+2]=t.z; in[16+4*c+3]=t.w;
    }

    float h[16];
#pragma unroll
    for (int k = 0; k < 16; ++k) h[k] = b1[k];
#pragma unroll
    for (int i = 0; i < 80; ++i)
#pragma unroll
        for (int k = 0; k < 16; ++k)
            h[k] = fmaf(in[i], W1[i*16 + k], h[k]);
#pragma unroll
    for (int k = 0; k < 16; ++k) h[k] = fmaxf(h[k], 0.0f);

    const int er = lane >> 4;
    const int jj = lane & 15;

#pragma unroll
    for (int j0 = 0; j0 < 64; j0 += 16) {
        float m[16];
#pragma unroll
        for (int t = 0; t < 16; ++t) m[t] = b2[j0 + t];
#pragma unroll
        for (int k = 0; k < 16; ++k)
#pragma unroll
            for (int t = 0; t < 16; ++t)
                m[t] = fmaf(h[k], W2[k*64 + j0 + t], m[t]);

        wave_lds_fence();
#pragma unroll
        for (int t = 0; t < 16; ++t) mld[lane][t] = fkey(m[t]);
        wave_lds_fence();

#pragma unroll
        for (int eg = 0; eg < 16; ++eg) {
            const int ee = (eg << 2) | er;
            atomicMax(&rkey[((size_t)dld[ee] << 6) + (unsigned)(j0 + jj)],
                      mld[ee][jj]);
        }
    }
}

extern "C" void kernel_launch(void* const* d_in, const int* in_sizes, int n_in,
                              void* d_out, int out_size, void* d_ws, size_t ws_size,
                              hipStream_t stream) {
    const float* x   = (const float*)d_in[0];
    const float* ef  = (const float*)d_in[1];
    const int*   src = (const int*)d_in[2];
    const int*   dst = (const int*)d_in[3];
    const float* mW1 = (const float*)d_in[4];
    const float* mb1 = (const float*)d_in[5];
    const float* mW2 = (const float*)d_in[6];
    const float* mb2 = (const float*)d_in[7];
    const float* uW1 = (const float*)d_in[8];
    const float* ub1 = (const float*)d_in[9];
    const float* uW2 = (const float*)d_in[10];
    const float* ub2 = (const float*)d_in[11];

    unsigned* rkey = (unsigned*)d_out;  // 50000*64 u32 = 12.8 MB, reuse d_out
    float*    out  = (float*)d_out;

    // ws layout (u32 units): deg[50000] | cursor[50000] | perm[800000] | dst_sorted[800000]
    const size_t WS_NEEDED = (size_t)(N_NODES + N_NODES + N_EDGES + N_EDGES) * 4;

    hipLaunchKernelGGL(init_kernel, dim3(3125), dim3(256), 0, stream, rkey);

    if (ws_size >= WS_NEEDED) {
        unsigned* deg        = (unsigned*)d_ws;
        unsigned* cursor     = deg + N_NODES;
        unsigned* perm       = cursor + N_NODES;
        int*      dst_sorted = (int*)(perm + N_EDGES);

        hipLaunchKernelGGL(zero_deg_kernel, dim3((N_NODES + 255) / 256), dim3(256), 0, stream, deg);
        hipLaunchKernelGGL(hist_kernel, dim3(3125), dim3(256), 0, stream, dst, deg);
        hipLaunchKernelGGL(scan_kernel, dim3(1), dim3(1024), 0, stream, deg, cursor);
        hipLaunchKernelGGL(scatter_kernel, dim3(3125), dim3(256), 0, stream, dst, cursor, perm, dst_sorted);
        hipLaunchKernelGGL(edge_csr_kernel, dim3(3125), dim3(256), 0, stream,
                           x, ef, src, perm, dst_sorted, mW1, mb1, mW2, mb2, rkey);
    } else {
        hipLaunchKernelGGL(edge_kernel, dim3(12500), dim3(64), 0, stream,
                           x, ef, src, dst, mW1, mb1, mW2, mb2, rkey);
    }

    hipLaunchKernelGGL(node_kernel, dim3((N_NODES + 255) / 256), dim3(256), 0, stream,
                       x, rkey, uW1, ub1, uW2, ub2, out);
}

// Round 4
// 223.352 us; speedup vs baseline: 1.1633x; 1.1633x over previous
//
#include <hip/hip_runtime.h>

#define N_NODES 50000
#define N_EDGES 800000
// D_FEAT=64, D_EDGE=16, D_HID=16, D_MSG=64, D_OUT=64

__device__ __forceinline__ unsigned fkey(float f) {
    unsigned u = __float_as_uint(f);
    return (u & 0x80000000u) ? ~u : (u | 0x80000000u);
}
// key(-inf) = ~0xFF800000 = 0x007FFFFF
#define KEY_NEG_INF 0x007FFFFFu

// wave-local LDS fence: per-wave private LDS region, DS pipe is in-order per
// wave; asm waitcnt + sched_barrier per guide rule 18. No s_barrier needed.
__device__ __forceinline__ void wave_lds_fence() {
    asm volatile("s_waitcnt lgkmcnt(0)" ::: "memory");
    __builtin_amdgcn_sched_barrier(0);
}

// ---------------- init: fill rkey with key(-inf) + zero deg ----------------
__global__ __launch_bounds__(256) void init_kernel(unsigned* __restrict__ rkey,
                                                   unsigned* __restrict__ deg) {
    const int i = blockIdx.x * 256 + threadIdx.x;  // 3125*256 = 800000 uint4 exact
    reinterpret_cast<uint4*>(rkey)[i] =
        make_uint4(KEY_NEG_INF, KEY_NEG_INF, KEY_NEG_INF, KEY_NEG_INF);
    if (i < N_NODES) deg[i] = 0u;
}

// ---------------- CSR build ----------------
__global__ __launch_bounds__(256) void hist_kernel(const int* __restrict__ dst,
                                                   unsigned* __restrict__ deg) {
    const int e = blockIdx.x * 256 + threadIdx.x;  // exact grid
    atomicAdd(&deg[dst[e]], 1u);
}

// scanA: 196 blocks x 256 threads. cursor[idx] = block-local exclusive prefix;
// bsum[b] = block total.
__global__ __launch_bounds__(256) void scanA_kernel(const unsigned* __restrict__ deg,
                                                    unsigned* __restrict__ cursor,
                                                    unsigned* __restrict__ bsum) {
    __shared__ unsigned wsum[4];
    const int t = threadIdx.x, b = blockIdx.x;
    const int idx = b * 256 + t;
    const int lane = t & 63, w = t >> 6;
    unsigned v = (idx < N_NODES) ? deg[idx] : 0u;
    const unsigned orig = v;
#pragma unroll
    for (int d = 1; d < 64; d <<= 1) {
        unsigned n = __shfl_up(v, d, 64);
        if (lane >= d) v += n;
    }
    if (lane == 63) wsum[w] = v;
    __syncthreads();
    unsigned woff = 0;
#pragma unroll
    for (int i = 0; i < 3; ++i) if (i < w) woff += wsum[i];
    if (idx < N_NODES) cursor[idx] = woff + v - orig;   // exclusive
    if (t == 255) bsum[b] = woff + v;                   // block total
}

// scanB: 1 block x 256: boff = exclusive scan of bsum[196]
__global__ __launch_bounds__(256) void scanB_kernel(const unsigned* __restrict__ bsum,
                                                    unsigned* __restrict__ boff) {
    __shared__ unsigned wsum[4];
    const int t = threadIdx.x;
    const int lane = t & 63, w = t >> 6;
    unsigned v = (t < 196) ? bsum[t] : 0u;
    const unsigned orig = v;
#pragma unroll
    for (int d = 1; d < 64; d <<= 1) {
        unsigned n = __shfl_up(v, d, 64);
        if (lane >= d) v += n;
    }
    if (lane == 63) wsum[w] = v;
    __syncthreads();
    unsigned woff = 0;
#pragma unroll
    for (int i = 0; i < 3; ++i) if (i < w) woff += wsum[i];
    if (t < 196) boff[t] = woff + v - orig;
}

// scatter: pos = boff[d>>8] + (cursor[d]++)  (cursor holds block-local starts)
__global__ __launch_bounds__(256) void scatter_kernel(const int* __restrict__ dst,
                                                      const unsigned* __restrict__ boff,
                                                      unsigned* __restrict__ cursor,
                                                      unsigned* __restrict__ perm,
                                                      int* __restrict__ dst_sorted) {
    const int e = blockIdx.x * 256 + threadIdx.x;  // exact grid
    const int d = dst[e];
    const unsigned pos = boff[d >> 8] + atomicAdd(&cursor[d], 1u);
    perm[pos] = (unsigned)e;
    dst_sorted[pos] = d;
}

// ---------------- edge kernel (CSR order, segmented reduce) ----------------
// 4 independent waves/block, wave = 64 CSR slots. Thread-per-edge MLP with
// uniform (s_load) weights; LDS transpose; per-quarter serial segmented max
// scan; plain coalesced store for complete segments, atomicMax only for
// boundary pieces.
__global__ __launch_bounds__(256) void edge_csr_kernel(
    const float* __restrict__ x, const float* __restrict__ ef,
    const int* __restrict__ src,
    const unsigned* __restrict__ perm, const int* __restrict__ dst_sorted,
    const float* __restrict__ W1, const float* __restrict__ b1,
    const float* __restrict__ W2, const float* __restrict__ b2,
    unsigned* __restrict__ rkey)
{
    const int lane = threadIdx.x & 63;
    const int w    = threadIdx.x >> 6;
    const int wave = blockIdx.x * 4 + w;
    const int base = wave * 64;
    const int slot = base + lane;

    __shared__ unsigned mld[4][64][17];
    __shared__ int      dldA[4][66];   // [w][0]=dst before base, [w][1+i]=slot i, [w][65]=dst after
    int* dld = &dldA[w][1];

    const int e = (int)perm[slot];
    const int d = dst_sorted[slot];
    dld[lane] = d;
    if (lane == 0)  dld[-1] = (base == 0) ? -1 : dst_sorted[base - 1];
    if (lane == 63) dld[64] = (base + 64 >= N_EDGES) ? -1 : dst_sorted[base + 64];

    // ---- load inputs: [edge_feats(16), x[src](64)] ----
    float in[80];
    const float4* efp = reinterpret_cast<const float4*>(ef) + (size_t)e * 4;
#pragma unroll
    for (int c = 0; c < 4; ++c) {
        float4 t = efp[c];
        in[4*c+0]=t.x; in[4*c+1]=t.y; in[4*c+2]=t.z; in[4*c+3]=t.w;
    }
    const int s = src[e];
    const float4* xp = reinterpret_cast<const float4*>(x) + (size_t)s * 16;
#pragma unroll
    for (int c = 0; c < 16; ++c) {
        float4 t = xp[c];
        in[16+4*c+0]=t.x; in[16+4*c+1]=t.y; in[16+4*c+2]=t.z; in[16+4*c+3]=t.w;
    }

    // ---- hidden: h = relu(in @ W1 + b1), W1[80][16] (uniform -> s_load) ----
    float h[16];
#pragma unroll
    for (int k = 0; k < 16; ++k) h[k] = b1[k];
#pragma unroll
    for (int i = 0; i < 80; ++i)
#pragma unroll
        for (int k = 0; k < 16; ++k)
            h[k] = fmaf(in[i], W1[i*16 + k], h[k]);
#pragma unroll
    for (int k = 0; k < 16; ++k) h[k] = fmaxf(h[k], 0.0f);

    const int q  = lane >> 4;   // quarter 0..3
    const int jj = lane & 15;   // feature within chunk

    // ---- output in chunks of 16 feats ----
#pragma unroll
    for (int j0 = 0; j0 < 64; j0 += 16) {
        float m[16];
#pragma unroll
        for (int t = 0; t < 16; ++t) m[t] = b2[j0 + t];
#pragma unroll
        for (int k = 0; k < 16; ++k)
#pragma unroll
            for (int t = 0; t < 16; ++t)
                m[t] = fmaf(h[k], W2[k*64 + j0 + t], m[t]);

        wave_lds_fence();               // prior chunk's scan reads done
#pragma unroll
        for (int t = 0; t < 16; ++t) mld[w][lane][t] = fkey(m[t]);
        wave_lds_fence();               // writes (incl. dld) visible to wave

        // ---- segmented max scan over this quarter's 16 slots ----
        const int s0 = q * 16;
        unsigned run = KEY_NEG_INF;
        int  dprev = dld[s0 - 1];       // dst just before the quarter (-1 sentinel)
        bool phead = (dld[s0] != dprev);
        dprev = dld[s0];
        run = mld[w][s0][jj];
#pragma unroll
        for (int i = 1; i < 16; ++i) {
            const int ss = s0 + i;
            const int ds = dld[ss];
            if (ds != dprev) {          // piece ends at ss-1; flush it
                unsigned* addr = &rkey[((size_t)dprev << 6) + (unsigned)(j0 + jj)];
                if (phead) *addr = run;          // complete segment: plain store
                else       atomicMax(addr, run);
                run = KEY_NEG_INF;
                phead = true;
            }
            run = max(run, mld[w][ss][jj]);
            dprev = ds;
        }
        const bool ptail = (dld[s0 + 16] != dprev);  // dld[64] covers q==3
        unsigned* addr = &rkey[((size_t)dprev << 6) + (unsigned)(j0 + jj)];
        if (phead && ptail) *addr = run;
        else                atomicMax(addr, run);
    }
}

// ---------------- node kernel: decode + update MLP ----------------
// rkey and out alias (both d_out); this thread reads its own row before
// writing it. No __restrict__ on those two.
__global__ __launch_bounds__(256) void node_kernel(
    const float* __restrict__ x, const unsigned* rkey,
    const float* __restrict__ W1, const float* __restrict__ b1,
    const float* __restrict__ W2, const float* __restrict__ b2,
    float* out)
{
    const int v = blockIdx.x * 256 + threadIdx.x;
    if (v >= N_NODES) return;

    float in[128];
    const float4* xp = reinterpret_cast<const float4*>(x) + (size_t)v * 16;
#pragma unroll
    for (int c = 0; c < 16; ++c) {
        float4 t = xp[c];
        in[4*c+0]=t.x; in[4*c+1]=t.y; in[4*c+2]=t.z; in[4*c+3]=t.w;
    }
    const uint4* rp = reinterpret_cast<const uint4*>(rkey) + (size_t)v * 16;
#pragma unroll
    for (int c = 0; c < 16; ++c) {
        uint4 t = rp[c];
        unsigned ks[4] = {t.x, t.y, t.z, t.w};
#pragma unroll
        for (int qq = 0; qq < 4; ++qq) {
            unsigned k = ks[qq];
            unsigned u = (k & 0x80000000u) ? (k ^ 0x80000000u) : ~k;
            float f = __uint_as_float(u);
            if (!(f >= -3.402823466e38f && f <= 3.402823466e38f)) f = 0.0f;
            in[64 + 4*c + qq] = f;
        }
    }

    float h[16];
#pragma unroll
    for (int k = 0; k < 16; ++k) h[k] = b1[k];
#pragma unroll
    for (int i = 0; i < 128; ++i)
#pragma unroll
        for (int k = 0; k < 16; ++k)
            h[k] = fmaf(in[i], W1[i*16 + k], h[k]);
#pragma unroll
    for (int k = 0; k < 16; ++k) h[k] = fmaxf(h[k], 0.0f);

    float* op = out + (size_t)v * 64;
#pragma unroll
    for (int c = 0; c < 16; ++c) {
        float oo[4];
#pragma unroll
        for (int qq = 0; qq < 4; ++qq) {
            float a = b2[4*c + qq];
#pragma unroll
            for (int k = 0; k < 16; ++k)
                a = fmaf(h[k], W2[k*64 + 4*c + qq], a);
            oo[qq] = a;
        }
        float4 o; o.x=oo[0]; o.y=oo[1]; o.z=oo[2]; o.w=oo[3];
        reinterpret_cast<float4*>(op)[c] = o;
    }
}

// ---------------- fallback edge kernel (direct atomics, round-2 path) ------
__global__ __launch_bounds__(64) void edge_kernel(
    const float* __restrict__ x, const float* __restrict__ ef,
    const int* __restrict__ src, const int* __restrict__ dst,
    const float* __restrict__ W1, const float* __restrict__ b1,
    const float* __restrict__ W2, const float* __restrict__ b2,
    unsigned* __restrict__ rkey)
{
    const int lane = threadIdx.x;
    const int e    = blockIdx.x * 64 + lane;

    __shared__ unsigned mld[64][17];
    __shared__ int      dld[64];

    float in[80];
    const float4* efp = reinterpret_cast<const float4*>(ef) + (size_t)e * 4;
#pragma unroll
    for (int c = 0; c < 4; ++c) {
        float4 t = efp[c];
        in[4*c+0]=t.x; in[4*c+1]=t.y; in[4*c+2]=t.z; in[4*c+3]=t.w;
    }
    const int s = src[e];
    dld[lane] = dst[e];
    const float4* xp = reinterpret_cast<const float4*>(x) + (size_t)s * 16;
#pragma unroll
    for (int c = 0; c < 16; ++c) {
        float4 t = xp[c];
        in[16+4*c+0]=t.x; in[16+4*c+1]=t.y; in[16+4*c+2]=t.z; in[16+4*c+3]=t.w;
    }

    float h[16];
#pragma unroll
    for (int k = 0; k < 16; ++k) h[k] = b1[k];
#pragma unroll
    for (int i = 0; i < 80; ++i)
#pragma unroll
        for (int k = 0; k < 16; ++k)
            h[k] = fmaf(in[i], W1[i*16 + k], h[k]);
#pragma unroll
    for (int k = 0; k < 16; ++k) h[k] = fmaxf(h[k], 0.0f);

    const int er = lane >> 4;
    const int jj = lane & 15;

#pragma unroll
    for (int j0 = 0; j0 < 64; j0 += 16) {
        float m[16];
#pragma unroll
        for (int t = 0; t < 16; ++t) m[t] = b2[j0 + t];
#pragma unroll
        for (int k = 0; k < 16; ++k)
#pragma unroll
            for (int t = 0; t < 16; ++t)
                m[t] = fmaf(h[k], W2[k*64 + j0 + t], m[t]);

        wave_lds_fence();
#pragma unroll
        for (int t = 0; t < 16; ++t) mld[lane][t] = fkey(m[t]);
        wave_lds_fence();

#pragma unroll
        for (int eg = 0; eg < 16; ++eg) {
            const int ee = (eg << 2) | er;
            atomicMax(&rkey[((size_t)dld[ee] << 6) + (unsigned)(j0 + jj)],
                      mld[ee][jj]);
        }
    }
}

extern "C" void kernel_launch(void* const* d_in, const int* in_sizes, int n_in,
                              void* d_out, int out_size, void* d_ws, size_t ws_size,
                              hipStream_t stream) {
    const float* x   = (const float*)d_in[0];
    const float* ef  = (const float*)d_in[1];
    const int*   src = (const int*)d_in[2];
    const int*   dst = (const int*)d_in[3];
    const float* mW1 = (const float*)d_in[4];
    const float* mb1 = (const float*)d_in[5];
    const float* mW2 = (const float*)d_in[6];
    const float* mb2 = (const float*)d_in[7];
    const float* uW1 = (const float*)d_in[8];
    const float* ub1 = (const float*)d_in[9];
    const float* uW2 = (const float*)d_in[10];
    const float* ub2 = (const float*)d_in[11];

    unsigned* rkey = (unsigned*)d_out;  // 50000*64 u32 = 12.8 MB, reuse d_out
    float*    out  = (float*)d_out;

    // ws layout (u32): deg[50000] | cursor[50000] | bsum[256] | boff[256]
    //                  | perm[800000] | dst_sorted[800000]
    const size_t WS_NEEDED = (size_t)(N_NODES * 2 + 512 + N_EDGES * 2) * 4;

    if (ws_size >= WS_NEEDED) {
        unsigned* deg        = (unsigned*)d_ws;
        unsigned* cursor     = deg + N_NODES;
        unsigned* bsum       = cursor + N_NODES;
        unsigned* boff       = bsum + 256;
        unsigned* perm       = boff + 256;
        int*      dst_sorted = (int*)(perm + N_EDGES);

        hipLaunchKernelGGL(init_kernel, dim3(3125), dim3(256), 0, stream, rkey, deg);
        hipLaunchKernelGGL(hist_kernel, dim3(3125), dim3(256), 0, stream, dst, deg);
        hipLaunchKernelGGL(scanA_kernel, dim3(196), dim3(256), 0, stream, deg, cursor, bsum);
        hipLaunchKernelGGL(scanB_kernel, dim3(1), dim3(256), 0, stream, bsum, boff);
        hipLaunchKernelGGL(scatter_kernel, dim3(3125), dim3(256), 0, stream,
                           dst, boff, cursor, perm, dst_sorted);
        hipLaunchKernelGGL(edge_csr_kernel, dim3(3125), dim3(256), 0, stream,
                           x, ef, src, perm, dst_sorted, mW1, mb1, mW2, mb2, rkey);
    } else {
        unsigned* dummy = (unsigned*)d_ws;  // deg unused in fallback; init still fills rkey
        hipLaunchKernelGGL(init_kernel, dim3(3125), dim3(256), 0, stream, rkey,
                           (ws_size >= (size_t)N_NODES * 4) ? dummy : rkey /*scratch alias, safe: overwritten*/);
        hipLaunchKernelGGL(edge_kernel, dim3(12500), dim3(64), 0, stream,
                           x, ef, src, dst, mW1, mb1, mW2, mb2, rkey);
    }

    hipLaunchKernelGGL(node_kernel, dim3((N_NODES + 255) / 256), dim3(256), 0, stream,
                       x, rkey, uW1, ub1, uW2, ub2, out);
}

// Round 5
// 199.864 us; speedup vs baseline: 1.3000x; 1.1175x over previous
//
#include <hip/hip_runtime.h>

#define N_NODES 50000
#define N_EDGES 800000
// D_FEAT=64, D_EDGE=16, D_HID=16, D_MSG=64, D_OUT=64

__device__ __forceinline__ unsigned fkey(float f) {
    unsigned u = __float_as_uint(f);
    return (u & 0x80000000u) ? ~u : (u | 0x80000000u);
}
// key(-inf) = ~0xFF800000 = 0x007FFFFF
#define KEY_NEG_INF 0x007FFFFFu

// wave-local LDS fence: per-wave private LDS region, DS pipe is in-order per
// wave; asm waitcnt + sched_barrier per guide rule 18. No s_barrier needed.
__device__ __forceinline__ void wave_lds_fence() {
    asm volatile("s_waitcnt lgkmcnt(0)" ::: "memory");
    __builtin_amdgcn_sched_barrier(0);
}

// ---------------- init: rkey fill + deg zero + xw precompute ----------------
// xw[v][k] = b1[k] + sum_i x[v][i] * W1[(16+i)*16 + k]   (folds x-part of
// layer 1 out of the per-edge kernel; 3.2 MB -> L2-resident per XCD)
__global__ __launch_bounds__(256) void init_kernel(
    unsigned* __restrict__ rkey, unsigned* __restrict__ deg,
    const float* __restrict__ x, const float* __restrict__ W1,
    const float* __restrict__ b1, float* __restrict__ xw)
{
    const int i = blockIdx.x * 256 + threadIdx.x;  // 3125*256 = 800000 exact
    reinterpret_cast<uint4*>(rkey)[i] =
        make_uint4(KEY_NEG_INF, KEY_NEG_INF, KEY_NEG_INF, KEY_NEG_INF);
    if (i < N_NODES) {
        deg[i] = 0u;
        float acc[16];
#pragma unroll
        for (int k = 0; k < 16; ++k) acc[k] = b1[k];
        const float4* xp = reinterpret_cast<const float4*>(x) + (size_t)i * 16;
#pragma unroll
        for (int c = 0; c < 16; ++c) {
            float4 t = xp[c];
            const float xv[4] = {t.x, t.y, t.z, t.w};
#pragma unroll
            for (int q = 0; q < 4; ++q) {
                const int row = 16 + 4 * c + q;   // W1 row (x part)
#pragma unroll
                for (int k = 0; k < 16; ++k)
                    acc[k] = fmaf(xv[q], W1[row * 16 + k], acc[k]);
            }
        }
        float4* op = reinterpret_cast<float4*>(xw) + (size_t)i * 4;
#pragma unroll
        for (int c = 0; c < 4; ++c) {
            float4 o; o.x = acc[4*c]; o.y = acc[4*c+1]; o.z = acc[4*c+2]; o.w = acc[4*c+3];
            op[c] = o;
        }
    }
}

// init for fallback path (rkey only)
__global__ __launch_bounds__(256) void init0_kernel(unsigned* __restrict__ rkey) {
    const int i = blockIdx.x * 256 + threadIdx.x;
    reinterpret_cast<uint4*>(rkey)[i] =
        make_uint4(KEY_NEG_INF, KEY_NEG_INF, KEY_NEG_INF, KEY_NEG_INF);
}

// ---------------- CSR build ----------------
__global__ __launch_bounds__(256) void hist_kernel(const int* __restrict__ dst,
                                                   unsigned* __restrict__ deg) {
    const int e = blockIdx.x * 256 + threadIdx.x;  // exact grid
    atomicAdd(&deg[dst[e]], 1u);
}

// scanA: 196 blocks x 256. cursor[idx] = block-local exclusive prefix;
// bsum[b] = block total.
__global__ __launch_bounds__(256) void scanA_kernel(const unsigned* __restrict__ deg,
                                                    unsigned* __restrict__ cursor,
                                                    unsigned* __restrict__ bsum) {
    __shared__ unsigned wsum[4];
    const int t = threadIdx.x, b = blockIdx.x;
    const int idx = b * 256 + t;
    const int lane = t & 63, w = t >> 6;
    unsigned v = (idx < N_NODES) ? deg[idx] : 0u;
    const unsigned orig = v;
#pragma unroll
    for (int d = 1; d < 64; d <<= 1) {
        unsigned n = __shfl_up(v, d, 64);
        if (lane >= d) v += n;
    }
    if (lane == 63) wsum[w] = v;
    __syncthreads();
    unsigned woff = 0;
#pragma unroll
    for (int i = 0; i < 3; ++i) if (i < w) woff += wsum[i];
    if (idx < N_NODES) cursor[idx] = woff + v - orig;   // exclusive
    if (t == 255) bsum[b] = woff + v;                   // block total
}

// scanB: 1 block x 256: boff = exclusive scan of bsum[196]
__global__ __launch_bounds__(256) void scanB_kernel(const unsigned* __restrict__ bsum,
                                                    unsigned* __restrict__ boff) {
    __shared__ unsigned wsum[4];
    const int t = threadIdx.x;
    const int lane = t & 63, w = t >> 6;
    unsigned v = (t < 196) ? bsum[t] : 0u;
    const unsigned orig = v;
#pragma unroll
    for (int d = 1; d < 64; d <<= 1) {
        unsigned n = __shfl_up(v, d, 64);
        if (lane >= d) v += n;
    }
    if (lane == 63) wsum[w] = v;
    __syncthreads();
    unsigned woff = 0;
#pragma unroll
    for (int i = 0; i < 3; ++i) if (i < w) woff += wsum[i];
    if (t < 196) boff[t] = woff + v - orig;
}

// scatter: one packed 8B write per edge: ds[pos] = (dst<<32) | e
__global__ __launch_bounds__(256) void scatter_kernel(const int* __restrict__ dst,
                                                      const unsigned* __restrict__ boff,
                                                      unsigned* __restrict__ cursor,
                                                      unsigned long long* __restrict__ ds) {
    const int e = blockIdx.x * 256 + threadIdx.x;  // exact grid
    const int d = dst[e];
    const unsigned pos = boff[d >> 8] + atomicAdd(&cursor[d], 1u);
    ds[pos] = ((unsigned long long)(unsigned)d << 32) | (unsigned)e;
}

// ---------------- edge kernel (CSR order, xw-folded, segmented reduce) -----
__global__ __launch_bounds__(256) void edge_csr_kernel(
    const float* __restrict__ xw, const float* __restrict__ ef,
    const unsigned long long* __restrict__ ds,
    const float* __restrict__ W1, const float* __restrict__ W2,
    const float* __restrict__ b2,
    unsigned* __restrict__ rkey)
{
    const int lane = threadIdx.x & 63;
    const int w    = threadIdx.x >> 6;
    const int wave = blockIdx.x * 4 + w;
    const int base = wave * 64;
    const int slot = base + lane;

    __shared__ unsigned mld[4][64][17];
    __shared__ int      dldA[4][66];
    int* dld = &dldA[w][1];

    const unsigned long long pv = ds[slot];
    const int e = (int)(unsigned)pv;
    const int d = (int)(pv >> 32);
    dld[lane] = d;
    if (lane == 0)  dld[-1] = (base == 0) ? -1 : (int)(ds[base - 1] >> 32);
    if (lane == 63) dld[64] = (base + 64 >= N_EDGES) ? -1 : (int)(ds[base + 64] >> 32);

    // ---- load ef row (16) ----
    float in[16];
    const float4* efp = reinterpret_cast<const float4*>(ef) + (size_t)e * 4;
#pragma unroll
    for (int c = 0; c < 4; ++c) {
        float4 t = efp[c];
        in[4*c+0]=t.x; in[4*c+1]=t.y; in[4*c+2]=t.z; in[4*c+3]=t.w;
    }
    // ---- h starts from xw[src] (bias + x-part folded) ----
    float h[16];
    const float4* xp = reinterpret_cast<const float4*>(xw) + (size_t)e /*temp*/ * 0 + (size_t)((unsigned)pv) * 0; // (no-op, kept simple below)
    {
        const int s_node_unused = 0; (void)s_node_unused;
    }
    // src index comes from e -> need src? NO: xw is indexed by src node. We
    // fold differently: xw is per-NODE; we need xw[src[e]]. Load src id from
    // packed? Not packed. Gather via src array:
    // (handled by caller passing xw pre-gathered? no) -- see below.
    // NOTE: src lookup kept: ds packs (dst,e); src[e] read here.
    h[0] = 0.0f; // placeholder overwritten below
    (void)h;
    // real load happens in second stage (see srcv)
    // ---- the above placeholder is resolved by reading src[e] from global ----
    // (separate pointer param avoided; see kernel signature change)
    // -- this comment block intentionally resolves below --
    float hh[16];
    (void)hh;
    // (dead code above eliminated by compiler; actual path:)
    // we re-declare properly:
    // [the actual implementation uses srcp param]
    // ---- output chunks ----
    // NOTE: this kernel body is replaced by edge_csr_kernel2 below.
}

// Clean implementation (edge kernel actually launched):
__global__ __launch_bounds__(256) void edge_csr2_kernel(
    const float* __restrict__ xw, const float* __restrict__ ef,
    const int* __restrict__ src,
    const unsigned long long* __restrict__ ds,
    const float* __restrict__ W1, const float* __restrict__ W2,
    const float* __restrict__ b2,
    unsigned* __restrict__ rkey)
{
    const int lane = threadIdx.x & 63;
    const int w    = threadIdx.x >> 6;
    const int wave = blockIdx.x * 4 + w;
    const int base = wave * 64;
    const int slot = base + lane;

    __shared__ unsigned mld[4][64][17];
    __shared__ int      dldA[4][66];
    int* dld = &dldA[w][1];

    const unsigned long long pv = ds[slot];
    const int e = (int)(unsigned)pv;
    const int d = (int)(pv >> 32);
    dld[lane] = d;
    if (lane == 0)  dld[-1] = (base == 0) ? -1 : (int)(ds[base - 1] >> 32);
    if (lane == 63) dld[64] = (base + 64 >= N_EDGES) ? -1 : (int)(ds[base + 64] >> 32);

    // ---- ef row (16 floats, random 64B gather) ----
    float in[16];
    const float4* efp = reinterpret_cast<const float4*>(ef) + (size_t)e * 4;
#pragma unroll
    for (int c = 0; c < 4; ++c) {
        float4 t = efp[c];
        in[4*c+0]=t.x; in[4*c+1]=t.y; in[4*c+2]=t.z; in[4*c+3]=t.w;
    }
    // ---- h = xw[src[e]] (64B gather, 3.2MB L2-resident) ----
    const int s = src[e];
    float h[16];
    const float4* xp = reinterpret_cast<const float4*>(xw) + (size_t)s * 4;
#pragma unroll
    for (int c = 0; c < 4; ++c) {
        float4 t = xp[c];
        h[4*c+0]=t.x; h[4*c+1]=t.y; h[4*c+2]=t.z; h[4*c+3]=t.w;
    }
    // ---- + ef @ W1[:16] ; relu ----
#pragma unroll
    for (int i = 0; i < 16; ++i)
#pragma unroll
        for (int k = 0; k < 16; ++k)
            h[k] = fmaf(in[i], W1[i*16 + k], h[k]);
#pragma unroll
    for (int k = 0; k < 16; ++k) h[k] = fmaxf(h[k], 0.0f);

    const int q  = lane >> 4;
    const int jj = lane & 15;

#pragma unroll
    for (int j0 = 0; j0 < 64; j0 += 16) {
        float m[16];
#pragma unroll
        for (int t = 0; t < 16; ++t) m[t] = b2[j0 + t];
#pragma unroll
        for (int k = 0; k < 16; ++k)
#pragma unroll
            for (int t = 0; t < 16; ++t)
                m[t] = fmaf(h[k], W2[k*64 + j0 + t], m[t]);

        wave_lds_fence();
#pragma unroll
        for (int t = 0; t < 16; ++t) mld[w][lane][t] = fkey(m[t]);
        wave_lds_fence();

        const int s0 = q * 16;
        unsigned run = KEY_NEG_INF;
        int  dprev = dld[s0 - 1];
        bool phead = (dld[s0] != dprev);
        dprev = dld[s0];
        run = mld[w][s0][jj];
#pragma unroll
        for (int i = 1; i < 16; ++i) {
            const int ss = s0 + i;
            const int dsv = dld[ss];
            if (dsv != dprev) {
                unsigned* addr = &rkey[((size_t)dprev << 6) + (unsigned)(j0 + jj)];
                if (phead) *addr = run;
                else       atomicMax(addr, run);
                run = KEY_NEG_INF;
                phead = true;
            }
            run = max(run, mld[w][ss][jj]);
            dprev = dsv;
        }
        const bool ptail = (dld[s0 + 16] != dprev);
        unsigned* addr = &rkey[((size_t)dprev << 6) + (unsigned)(j0 + jj)];
        if (phead && ptail) *addr = run;
        else                atomicMax(addr, run);
    }
}

// ---------------- node kernel: decode + update MLP ----------------
__global__ __launch_bounds__(256) void node_kernel(
    const float* __restrict__ x, const unsigned* rkey,
    const float* __restrict__ W1, const float* __restrict__ b1,
    const float* __restrict__ W2, const float* __restrict__ b2,
    float* out)
{
    const int v = blockIdx.x * 256 + threadIdx.x;
    if (v >= N_NODES) return;

    float in[128];
    const float4* xp = reinterpret_cast<const float4*>(x) + (size_t)v * 16;
#pragma unroll
    for (int c = 0; c < 16; ++c) {
        float4 t = xp[c];
        in[4*c+0]=t.x; in[4*c+1]=t.y; in[4*c+2]=t.z; in[4*c+3]=t.w;
    }
    const uint4* rp = reinterpret_cast<const uint4*>(rkey) + (size_t)v * 16;
#pragma unroll
    for (int c = 0; c < 16; ++c) {
        uint4 t = rp[c];
        unsigned ks[4] = {t.x, t.y, t.z, t.w};
#pragma unroll
        for (int qq = 0; qq < 4; ++qq) {
            unsigned k = ks[qq];
            unsigned u = (k & 0x80000000u) ? (k ^ 0x80000000u) : ~k;
            float f = __uint_as_float(u);
            if (!(f >= -3.402823466e38f && f <= 3.402823466e38f)) f = 0.0f;
            in[64 + 4*c + qq] = f;
        }
    }

    float h[16];
#pragma unroll
    for (int k = 0; k < 16; ++k) h[k] = b1[k];
#pragma unroll
    for (int i = 0; i < 128; ++i)
#pragma unroll
        for (int k = 0; k < 16; ++k)
            h[k] = fmaf(in[i], W1[i*16 + k], h[k]);
#pragma unroll
    for (int k = 0; k < 16; ++k) h[k] = fmaxf(h[k], 0.0f);

    float* op = out + (size_t)v * 64;
#pragma unroll
    for (int c = 0; c < 16; ++c) {
        float oo[4];
#pragma unroll
        for (int qq = 0; qq < 4; ++qq) {
            float a = b2[4*c + qq];
#pragma unroll
            for (int k = 0; k < 16; ++k)
                a = fmaf(h[k], W2[k*64 + 4*c + qq], a);
            oo[qq] = a;
        }
        float4 o; o.x=oo[0]; o.y=oo[1]; o.z=oo[2]; o.w=oo[3];
        reinterpret_cast<float4*>(op)[c] = o;
    }
}

// ---------------- fallback edge kernel (direct atomics, no ws) ------------
__global__ __launch_bounds__(64) void edge_kernel(
    const float* __restrict__ x, const float* __restrict__ ef,
    const int* __restrict__ src, const int* __restrict__ dst,
    const float* __restrict__ W1, const float* __restrict__ b1,
    const float* __restrict__ W2, const float* __restrict__ b2,
    unsigned* __restrict__ rkey)
{
    const int lane = threadIdx.x;
    const int e    = blockIdx.x * 64 + lane;

    __shared__ unsigned mld[64][17];
    __shared__ int      dld[64];

    float in[80];
    const float4* efp = reinterpret_cast<const float4*>(ef) + (size_t)e * 4;
#pragma unroll
    for (int c = 0; c < 4; ++c) {
        float4 t = efp[c];
        in[4*c+0]=t.x; in[4*c+1]=t.y; in[4*c+2]=t.z; in[4*c+3]=t.w;
    }
    const int s = src[e];
    dld[lane] = dst[e];
    const float4* xp = reinterpret_cast<const float4*>(x) + (size_t)s * 16;
#pragma unroll
    for (int c = 0; c < 16; ++c) {
        float4 t = xp[c];
        in[16+4*c+0]=t.x; in[16+4*c+1]=t.y; in[16+4*c+2]=t.z; in[16+4*c+3]=t.w;
    }

    float h[16];
#pragma unroll
    for (int k = 0; k < 16; ++k) h[k] = b1[k];
#pragma unroll
    for (int i = 0; i < 80; ++i)
#pragma unroll
        for (int k = 0; k < 16; ++k)
            h[k] = fmaf(in[i], W1[i*16 + k], h[k]);
#pragma unroll
    for (int k = 0; k < 16; ++k) h[k] = fmaxf(h[k], 0.0f);

    const int er = lane >> 4;
    const int jj = lane & 15;

#pragma unroll
    for (int j0 = 0; j0 < 64; j0 += 16) {
        float m[16];
#pragma unroll
        for (int t = 0; t < 16; ++t) m[t] = b2[j0 + t];
#pragma unroll
        for (int k = 0; k < 16; ++k)
#pragma unroll
            for (int t = 0; t < 16; ++t)
                m[t] = fmaf(h[k], W2[k*64 + j0 + t], m[t]);

        wave_lds_fence();
#pragma unroll
        for (int t = 0; t < 16; ++t) mld[lane][t] = fkey(m[t]);
        wave_lds_fence();

#pragma unroll
        for (int eg = 0; eg < 16; ++eg) {
            const int ee = (eg << 2) | er;
            atomicMax(&rkey[((size_t)dld[ee] << 6) + (unsigned)(j0 + jj)],
                      mld[ee][jj]);
        }
    }
}

extern "C" void kernel_launch(void* const* d_in, const int* in_sizes, int n_in,
                              void* d_out, int out_size, void* d_ws, size_t ws_size,
                              hipStream_t stream) {
    const float* x   = (const float*)d_in[0];
    const float* ef  = (const float*)d_in[1];
    const int*   src = (const int*)d_in[2];
    const int*   dst = (const int*)d_in[3];
    const float* mW1 = (const float*)d_in[4];
    const float* mb1 = (const float*)d_in[5];
    const float* mW2 = (const float*)d_in[6];
    const float* mb2 = (const float*)d_in[7];
    const float* uW1 = (const float*)d_in[8];
    const float* ub1 = (const float*)d_in[9];
    const float* uW2 = (const float*)d_in[10];
    const float* ub2 = (const float*)d_in[11];

    unsigned* rkey = (unsigned*)d_out;  // 50000*64 u32 = 12.8 MB, reuse d_out
    float*    out  = (float*)d_out;

    // ws layout: deg[50000] u32 | cursor[50000] u32 | bsum[256] | boff[256]
    //            | xw[800000] f32 | ds[800000] u64   (total ~10.0 MB)
    const size_t WS_NEEDED = (size_t)(N_NODES * 2 + 512 + N_EDGES) * 4
                           + (size_t)N_EDGES * 8;

    if (ws_size >= WS_NEEDED) {
        unsigned* deg    = (unsigned*)d_ws;
        unsigned* cursor = deg + N_NODES;
        unsigned* bsum   = cursor + N_NODES;
        unsigned* boff   = bsum + 256;
        float*    xw     = (float*)(boff + 256);
        unsigned long long* ds = (unsigned long long*)(xw + N_EDGES); // 800000 f32 = 50000*16

        hipLaunchKernelGGL(init_kernel, dim3(3125), dim3(256), 0, stream,
                           rkey, deg, x, mW1, mb1, xw);
        hipLaunchKernelGGL(hist_kernel, dim3(3125), dim3(256), 0, stream, dst, deg);
        hipLaunchKernelGGL(scanA_kernel, dim3(196), dim3(256), 0, stream, deg, cursor, bsum);
        hipLaunchKernelGGL(scanB_kernel, dim3(1), dim3(256), 0, stream, bsum, boff);
        hipLaunchKernelGGL(scatter_kernel, dim3(3125), dim3(256), 0, stream,
                           dst, boff, cursor, ds);
        hipLaunchKernelGGL(edge_csr2_kernel, dim3(3125), dim3(256), 0, stream,
                           xw, ef, src, ds, mW1, mW2, mb2, rkey);
    } else {
        hipLaunchKernelGGL(init0_kernel, dim3(3125), dim3(256), 0, stream, rkey);
        hipLaunchKernelGGL(edge_kernel, dim3(12500), dim3(64), 0, stream,
                           x, ef, src, dst, mW1, mb1, mW2, mb2, rkey);
    }

    hipLaunchKernelGGL(node_kernel, dim3((N_NODES + 255) / 256), dim3(256), 0, stream,
                       x, rkey, uW1, ub1, uW2, ub2, out);
}

// Round 6
// 141.085 us; speedup vs baseline: 1.8416x; 1.4166x over previous
//
#include <hip/hip_runtime.h>

#define N_NODES 50000
#define N_EDGES 800000
// D_FEAT=64, D_EDGE=16, D_HID=16, D_MSG=64, D_OUT=64

#define NB  196    // coarse buckets (256 nodes each; 196*256 = 50176 >= 50000)
#define PB  128    // partition blocks
#define EPB 6250   // edges per partition block (128*6250 = 800000 exact)
#define PITERS 25  // ceil(6250/256)
#define CAP 7680   // finesort LDS staging capacity (max bucket ~4.4k, huge margin)

__device__ __forceinline__ unsigned fkey(float f) {
    unsigned u = __float_as_uint(f);
    return (u & 0x80000000u) ? ~u : (u | 0x80000000u);
}
#define KEY_NEG_INF 0x007FFFFFu  // key(-inf)

// wave-local LDS fence (per-wave private LDS region; DS pipe in-order per wave)
__device__ __forceinline__ void wave_lds_fence() {
    asm volatile("s_waitcnt lgkmcnt(0)" ::: "memory");
    __builtin_amdgcn_sched_barrier(0);
}

// ---------------- coarse hist: per-block LDS hist of dst>>8 ----------------
__global__ __launch_bounds__(256) void chist_kernel(const int* __restrict__ dst,
                                                    unsigned* __restrict__ bcnt) {
    __shared__ unsigned lh[NB];
    const int t = threadIdx.x, b = blockIdx.x;
    if (t < NB) lh[t] = 0u;
    __syncthreads();
    const int e0 = b * EPB;
#pragma unroll
    for (int it = 0; it < PITERS; ++it) {
        const int i = it * 256 + t;
        if (i < EPB) atomicAdd(&lh[(unsigned)dst[e0 + i] >> 8], 1u);
    }
    __syncthreads();
    if (t < NB) bcnt[b * NB + t] = lh[t];
}

// ---------------- cscan: per-(block,bucket) deterministic offsets ----------
__global__ __launch_bounds__(256) void cscan_kernel(const unsigned* __restrict__ bcnt,
                                                    unsigned* __restrict__ gstart,
                                                    unsigned* __restrict__ boffG,
                                                    unsigned* __restrict__ totG) {
    __shared__ unsigned wsum[4];
    const int t = threadIdx.x, lane = t & 63, w = t >> 6;
    unsigned tot = 0;
    if (t < NB)
        for (int k = 0; k < PB; ++k) tot += bcnt[k * NB + t];
    unsigned v = (t < NB) ? tot : 0u;
    const unsigned orig = v;
#pragma unroll
    for (int d = 1; d < 64; d <<= 1) {
        unsigned n = __shfl_up(v, d, 64);
        if (lane >= d) v += n;
    }
    if (lane == 63) wsum[w] = v;
    __syncthreads();
    unsigned woff = 0;
#pragma unroll
    for (int i = 0; i < 3; ++i) if (i < w) woff += wsum[i];
    const unsigned boff = woff + v - orig;  // exclusive scan of tot
    if (t < NB) {
        boffG[t] = boff;
        totG[t]  = tot;
        unsigned run = boff;
        for (int k = 0; k < PB; ++k) { gstart[k * NB + t] = run; run += bcnt[k * NB + t]; }
    }
}

// ---------------- partition: LDS-staged coarse binning, coalesced flush ----
__global__ __launch_bounds__(256) void partition_kernel(const int* __restrict__ dst,
                                                        const unsigned* __restrict__ gstart,
                                                        unsigned long long* __restrict__ part) {
    __shared__ unsigned long long st[EPB];      // 50 KB
    __shared__ unsigned lh[NB], lstart[NB], lc[NB], gs[NB];
    __shared__ unsigned wsum[4];
    const int t = threadIdx.x, b = blockIdx.x, lane = t & 63, w = t >> 6;
    if (t < NB) { lh[t] = 0u; gs[t] = gstart[b * NB + t]; }
    __syncthreads();
    const int e0 = b * EPB;
#pragma unroll
    for (int it = 0; it < PITERS; ++it) {
        const int i = it * 256 + t;
        if (i < EPB) atomicAdd(&lh[(unsigned)dst[e0 + i] >> 8], 1u);
    }
    __syncthreads();
    {   // exclusive scan lh -> lstart (and cursor lc)
        unsigned v = (t < NB) ? lh[t] : 0u;
        const unsigned orig = v;
#pragma unroll
        for (int d = 1; d < 64; d <<= 1) {
            unsigned n = __shfl_up(v, d, 64);
            if (lane >= d) v += n;
        }
        if (lane == 63) wsum[w] = v;
        __syncthreads();
        unsigned woff = 0;
#pragma unroll
        for (int i = 0; i < 3; ++i) if (i < w) woff += wsum[i];
        if (t < NB) { lstart[t] = woff + v - orig; lc[t] = woff + v - orig; }
    }
    __syncthreads();
#pragma unroll
    for (int it = 0; it < PITERS; ++it) {
        const int i = it * 256 + t;
        if (i < EPB) {
            const int e = e0 + i;
            const unsigned d = (unsigned)dst[e];
            const unsigned p = atomicAdd(&lc[d >> 8], 1u);
            st[p] = ((unsigned long long)d << 32) | (unsigned)e;
        }
    }
    __syncthreads();
#pragma unroll
    for (int it = 0; it < PITERS; ++it) {
        const int i = it * 256 + t;
        if (i < EPB) {
            const unsigned long long pv = st[i];
            const unsigned bkt = (unsigned)(pv >> 40);      // d>>8
            part[gs[bkt] + ((unsigned)i - lstart[bkt])] = pv;
        }
    }
}

// ---------------- finesort: sort one coarse bucket by exact dst ------------
__global__ __launch_bounds__(256) void finesort_kernel(const unsigned long long* __restrict__ part,
                                                       const unsigned* __restrict__ boffG,
                                                       const unsigned* __restrict__ totG,
                                                       unsigned long long* __restrict__ dsf) {
    __shared__ unsigned long long st[CAP];      // 60 KB
    __shared__ unsigned fh[256], fstart[256];
    __shared__ unsigned wsum[4];
    const int t = threadIdx.x, b = blockIdx.x, lane = t & 63, w = t >> 6;
    const unsigned base = boffG[b], cnt = totG[b];
    fh[t] = 0u;
    __syncthreads();
    const int iters = (int)((cnt + 255u) >> 8);
    for (int it = 0; it < iters; ++it) {
        const unsigned i = (unsigned)it * 256u + (unsigned)t;
        if (i < cnt) atomicAdd(&fh[(unsigned)(part[base + i] >> 32) & 255u], 1u);
    }
    __syncthreads();
    {   // exclusive scan fh -> fstart (doubles as scatter cursor)
        unsigned v = fh[t];
        const unsigned orig = v;
#pragma unroll
        for (int d = 1; d < 64; d <<= 1) {
            unsigned n = __shfl_up(v, d, 64);
            if (lane >= d) v += n;
        }
        if (lane == 63) wsum[w] = v;
        __syncthreads();
        unsigned woff = 0;
#pragma unroll
        for (int i = 0; i < 3; ++i) if (i < w) woff += wsum[i];
        fstart[t] = woff + v - orig;
    }
    __syncthreads();
    if (cnt <= CAP) {
        for (int it = 0; it < iters; ++it) {
            const unsigned i = (unsigned)it * 256u + (unsigned)t;
            if (i < cnt) {
                const unsigned long long pv = part[base + i];
                const unsigned p = atomicAdd(&fstart[(unsigned)(pv >> 32) & 255u], 1u);
                st[p] = pv;
            }
        }
        __syncthreads();
        for (int it = 0; it < iters; ++it) {
            const unsigned i = (unsigned)it * 256u + (unsigned)t;
            if (i < cnt) dsf[base + i] = st[i];     // fully coalesced
        }
    } else {  // overflow fallback (statistically unreachable): direct dense scatter
        for (int it = 0; it < iters; ++it) {
            const unsigned i = (unsigned)it * 256u + (unsigned)t;
            if (i < cnt) {
                const unsigned long long pv = part[base + i];
                const unsigned p = atomicAdd(&fstart[(unsigned)(pv >> 32) & 255u], 1u);
                dsf[base + p] = pv;
            }
        }
    }
}

// ---------------- init: rkey fill + xw precompute --------------------------
// xw[v][k] = b1[k] + sum_i x[v][i] * W1[(16+i)*16 + k]
__global__ __launch_bounds__(256) void init_kernel(
    unsigned* __restrict__ rkey,
    const float* __restrict__ x, const float* __restrict__ W1,
    const float* __restrict__ b1, float* __restrict__ xw)
{
    const int i = blockIdx.x * 256 + threadIdx.x;  // 3125*256 = 800000 exact
    reinterpret_cast<uint4*>(rkey)[i] =
        make_uint4(KEY_NEG_INF, KEY_NEG_INF, KEY_NEG_INF, KEY_NEG_INF);
    if (i < N_NODES) {
        float acc[16];
#pragma unroll
        for (int k = 0; k < 16; ++k) acc[k] = b1[k];
        const float4* xp = reinterpret_cast<const float4*>(x) + (size_t)i * 16;
#pragma unroll
        for (int c = 0; c < 16; ++c) {
            float4 tv = xp[c];
            const float xv[4] = {tv.x, tv.y, tv.z, tv.w};
#pragma unroll
            for (int q = 0; q < 4; ++q) {
                const int row = 16 + 4 * c + q;
#pragma unroll
                for (int k = 0; k < 16; ++k)
                    acc[k] = fmaf(xv[q], W1[row * 16 + k], acc[k]);
            }
        }
        float4* op = reinterpret_cast<float4*>(xw) + (size_t)i * 4;
#pragma unroll
        for (int c = 0; c < 4; ++c) {
            float4 o; o.x = acc[4*c]; o.y = acc[4*c+1]; o.z = acc[4*c+2]; o.w = acc[4*c+3];
            op[c] = o;
        }
    }
}

__global__ __launch_bounds__(256) void init0_kernel(unsigned* __restrict__ rkey) {
    const int i = blockIdx.x * 256 + threadIdx.x;
    reinterpret_cast<uint4*>(rkey)[i] =
        make_uint4(KEY_NEG_INF, KEY_NEG_INF, KEY_NEG_INF, KEY_NEG_INF);
}

// ---------------- edge kernel (CSR order, xw-folded, segmented reduce) -----
__global__ __launch_bounds__(256) void edge_csr2_kernel(
    const float* __restrict__ xw, const float* __restrict__ ef,
    const int* __restrict__ src,
    const unsigned long long* __restrict__ ds,
    const float* __restrict__ W1, const float* __restrict__ W2,
    const float* __restrict__ b2,
    unsigned* __restrict__ rkey)
{
    const int lane = threadIdx.x & 63;
    const int w    = threadIdx.x >> 6;
    const int wave = blockIdx.x * 4 + w;
    const int base = wave * 64;
    const int slot = base + lane;

    __shared__ unsigned mld[4][64][17];
    __shared__ int      dldA[4][66];
    int* dld = &dldA[w][1];

    const unsigned long long pv = ds[slot];
    const int e = (int)(unsigned)pv;
    const int d = (int)(pv >> 32);
    dld[lane] = d;
    if (lane == 0)  dld[-1] = (base == 0) ? -1 : (int)(ds[base - 1] >> 32);
    if (lane == 63) dld[64] = (base + 64 >= N_EDGES) ? -1 : (int)(ds[base + 64] >> 32);

    // ---- ef row (16 floats, random 64B gather) ----
    float in[16];
    const float4* efp = reinterpret_cast<const float4*>(ef) + (size_t)e * 4;
#pragma unroll
    for (int c = 0; c < 4; ++c) {
        float4 tv = efp[c];
        in[4*c+0]=tv.x; in[4*c+1]=tv.y; in[4*c+2]=tv.z; in[4*c+3]=tv.w;
    }
    // ---- h = xw[src[e]] (64B gather, 3.2MB L2-resident) ----
    const int s = src[e];
    float h[16];
    const float4* xp = reinterpret_cast<const float4*>(xw) + (size_t)s * 4;
#pragma unroll
    for (int c = 0; c < 4; ++c) {
        float4 tv = xp[c];
        h[4*c+0]=tv.x; h[4*c+1]=tv.y; h[4*c+2]=tv.z; h[4*c+3]=tv.w;
    }
    // ---- + ef @ W1[:16] ; relu ----
#pragma unroll
    for (int i = 0; i < 16; ++i)
#pragma unroll
        for (int k = 0; k < 16; ++k)
            h[k] = fmaf(in[i], W1[i*16 + k], h[k]);
#pragma unroll
    for (int k = 0; k < 16; ++k) h[k] = fmaxf(h[k], 0.0f);

    const int q  = lane >> 4;
    const int jj = lane & 15;

#pragma unroll
    for (int j0 = 0; j0 < 64; j0 += 16) {
        float m[16];
#pragma unroll
        for (int t = 0; t < 16; ++t) m[t] = b2[j0 + t];
#pragma unroll
        for (int k = 0; k < 16; ++k)
#pragma unroll
            for (int t = 0; t < 16; ++t)
                m[t] = fmaf(h[k], W2[k*64 + j0 + t], m[t]);

        wave_lds_fence();
#pragma unroll
        for (int t = 0; t < 16; ++t) mld[w][lane][t] = fkey(m[t]);
        wave_lds_fence();

        const int s0 = q * 16;
        unsigned run = KEY_NEG_INF;
        int  dprev = dld[s0 - 1];
        bool phead = (dld[s0] != dprev);
        dprev = dld[s0];
        run = mld[w][s0][jj];
#pragma unroll
        for (int i = 1; i < 16; ++i) {
            const int ss = s0 + i;
            const int dsv = dld[ss];
            if (dsv != dprev) {
                unsigned* addr = &rkey[((size_t)dprev << 6) + (unsigned)(j0 + jj)];
                if (phead) *addr = run;
                else       atomicMax(addr, run);
                run = KEY_NEG_INF;
                phead = true;
            }
            run = max(run, mld[w][ss][jj]);
            dprev = dsv;
        }
        const bool ptail = (dld[s0 + 16] != dprev);
        unsigned* addr = &rkey[((size_t)dprev << 6) + (unsigned)(j0 + jj)];
        if (phead && ptail) *addr = run;
        else                atomicMax(addr, run);
    }
}

// ---------------- node kernel: decode + update MLP ----------------
// rkey and out alias (both d_out); each thread reads its row before writing it.
__global__ __launch_bounds__(256) void node_kernel(
    const float* __restrict__ x, const unsigned* rkey,
    const float* __restrict__ W1, const float* __restrict__ b1,
    const float* __restrict__ W2, const float* __restrict__ b2,
    float* out)
{
    const int v = blockIdx.x * 256 + threadIdx.x;
    if (v >= N_NODES) return;

    float in[128];
    const float4* xp = reinterpret_cast<const float4*>(x) + (size_t)v * 16;
#pragma unroll
    for (int c = 0; c < 16; ++c) {
        float4 tv = xp[c];
        in[4*c+0]=tv.x; in[4*c+1]=tv.y; in[4*c+2]=tv.z; in[4*c+3]=tv.w;
    }
    const uint4* rp = reinterpret_cast<const uint4*>(rkey) + (size_t)v * 16;
#pragma unroll
    for (int c = 0; c < 16; ++c) {
        uint4 tv = rp[c];
        unsigned ks[4] = {tv.x, tv.y, tv.z, tv.w};
#pragma unroll
        for (int qq = 0; qq < 4; ++qq) {
            unsigned k = ks[qq];
            unsigned u = (k & 0x80000000u) ? (k ^ 0x80000000u) : ~k;
            float f = __uint_as_float(u);
            if (!(f >= -3.402823466e38f && f <= 3.402823466e38f)) f = 0.0f;
            in[64 + 4*c + qq] = f;
        }
    }

    float h[16];
#pragma unroll
    for (int k = 0; k < 16; ++k) h[k] = b1[k];
#pragma unroll
    for (int i = 0; i < 128; ++i)
#pragma unroll
        for (int k = 0; k < 16; ++k)
            h[k] = fmaf(in[i], W1[i*16 + k], h[k]);
#pragma unroll
    for (int k = 0; k < 16; ++k) h[k] = fmaxf(h[k], 0.0f);

    float* op = out + (size_t)v * 64;
#pragma unroll
    for (int c = 0; c < 16; ++c) {
        float oo[4];
#pragma unroll
        for (int qq = 0; qq < 4; ++qq) {
            float a = b2[4*c + qq];
#pragma unroll
            for (int k = 0; k < 16; ++k)
                a = fmaf(h[k], W2[k*64 + 4*c + qq], a);
            oo[qq] = a;
        }
        float4 o; o.x=oo[0]; o.y=oo[1]; o.z=oo[2]; o.w=oo[3];
        reinterpret_cast<float4*>(op)[c] = o;
    }
}

// ---------------- fallback edge kernel (direct atomics, no ws) ------------
__global__ __launch_bounds__(64) void edge_kernel(
    const float* __restrict__ x, const float* __restrict__ ef,
    const int* __restrict__ src, const int* __restrict__ dst,
    const float* __restrict__ W1, const float* __restrict__ b1,
    const float* __restrict__ W2, const float* __restrict__ b2,
    unsigned* __restrict__ rkey)
{
    const int lane = threadIdx.x;
    const int e    = blockIdx.x * 64 + lane;

    __shared__ unsigned mld[64][17];
    __shared__ int      dld[64];

    float in[80];
    const float4* efp = reinterpret_cast<const float4*>(ef) + (size_t)e * 4;
#pragma unroll
    for (int c = 0; c < 4; ++c) {
        float4 tv = efp[c];
        in[4*c+0]=tv.x; in[4*c+1]=tv.y; in[4*c+2]=tv.z; in[4*c+3]=tv.w;
    }
    const int s = src[e];
    dld[lane] = dst[e];
    const float4* xp = reinterpret_cast<const float4*>(x) + (size_t)s * 16;
#pragma unroll
    for (int c = 0; c < 16; ++c) {
        float4 tv = xp[c];
        in[16+4*c+0]=tv.x; in[16+4*c+1]=tv.y; in[16+4*c+2]=tv.z; in[16+4*c+3]=tv.w;
    }

    float h[16];
#pragma unroll
    for (int k = 0; k < 16; ++k) h[k] = b1[k];
#pragma unroll
    for (int i = 0; i < 80; ++i)
#pragma unroll
        for (int k = 0; k < 16; ++k)
            h[k] = fmaf(in[i], W1[i*16 + k], h[k]);
#pragma unroll
    for (int k = 0; k < 16; ++k) h[k] = fmaxf(h[k], 0.0f);

    const int er = lane >> 4;
    const int jj = lane & 15;

#pragma unroll
    for (int j0 = 0; j0 < 64; j0 += 16) {
        float m[16];
#pragma unroll
        for (int t = 0; t < 16; ++t) m[t] = b2[j0 + t];
#pragma unroll
        for (int k = 0; k < 16; ++k)
#pragma unroll
            for (int t = 0; t < 16; ++t)
                m[t] = fmaf(h[k], W2[k*64 + j0 + t], m[t]);

        wave_lds_fence();
#pragma unroll
        for (int t = 0; t < 16; ++t) mld[lane][t] = fkey(m[t]);
        wave_lds_fence();

#pragma unroll
        for (int eg = 0; eg < 16; ++eg) {
            const int ee = (eg << 2) | er;
            atomicMax(&rkey[((size_t)dld[ee] << 6) + (unsigned)(j0 + jj)],
                      mld[ee][jj]);
        }
    }
}

extern "C" void kernel_launch(void* const* d_in, const int* in_sizes, int n_in,
                              void* d_out, int out_size, void* d_ws, size_t ws_size,
                              hipStream_t stream) {
    const float* x   = (const float*)d_in[0];
    const float* ef  = (const float*)d_in[1];
    const int*   src = (const int*)d_in[2];
    const int*   dst = (const int*)d_in[3];
    const float* mW1 = (const float*)d_in[4];
    const float* mb1 = (const float*)d_in[5];
    const float* mW2 = (const float*)d_in[6];
    const float* mb2 = (const float*)d_in[7];
    const float* uW1 = (const float*)d_in[8];
    const float* ub1 = (const float*)d_in[9];
    const float* uW2 = (const float*)d_in[10];
    const float* ub2 = (const float*)d_in[11];

    unsigned* rkey = (unsigned*)d_out;  // 50000*64 u32 = 12.8 MB
    float*    out  = (float*)d_out;

    // ws layout: dsf u64[800000] | bcnt u32[PB*NB] | gstart u32[PB*NB]
    //            | boffG u32[256] | totG u32[256] | xw f32[800000]   (~9.8 MB)
    const size_t WS_NEEDED = (size_t)N_EDGES * 8
                           + (size_t)(PB * NB * 2 + 512 + N_EDGES) * 4;

    if (ws_size >= WS_NEEDED) {
        unsigned long long* dsf = (unsigned long long*)d_ws;
        unsigned* bcnt   = (unsigned*)(dsf + N_EDGES);
        unsigned* gstart = bcnt + PB * NB;
        unsigned* boffG  = gstart + PB * NB;
        unsigned* totG   = boffG + 256;
        float*    xw     = (float*)(totG + 256);
        unsigned long long* part = (unsigned long long*)d_out;  // 6.4 MB temp, freed before init

        hipLaunchKernelGGL(chist_kernel,     dim3(PB),   dim3(256), 0, stream, dst, bcnt);
        hipLaunchKernelGGL(cscan_kernel,     dim3(1),    dim3(256), 0, stream, bcnt, gstart, boffG, totG);
        hipLaunchKernelGGL(partition_kernel, dim3(PB),   dim3(256), 0, stream, dst, gstart, part);
        hipLaunchKernelGGL(finesort_kernel,  dim3(NB),   dim3(256), 0, stream, part, boffG, totG, dsf);
        hipLaunchKernelGGL(init_kernel,      dim3(3125), dim3(256), 0, stream, rkey, x, mW1, mb1, xw);
        hipLaunchKernelGGL(edge_csr2_kernel, dim3(3125), dim3(256), 0, stream,
                           xw, ef, src, dsf, mW1, mW2, mb2, rkey);
    } else {
        hipLaunchKernelGGL(init0_kernel, dim3(3125), dim3(256), 0, stream, rkey);
        hipLaunchKernelGGL(edge_kernel, dim3(12500), dim3(64), 0, stream,
                           x, ef, src, dst, mW1, mb1, mW2, mb2, rkey);
    }

    hipLaunchKernelGGL(node_kernel, dim3((N_NODES + 255) / 256), dim3(256), 0, stream,
                       x, rkey, uW1, ub1, uW2, ub2, out);
}